// Round 1
// baseline (638.356 us; speedup 1.0000x reference)
//
#include <hip/hip_runtime.h>

// VarDecoder: N=256, CAT_IN=1024, H=512, V=32000, T=8
// out[n][t][v] fp32, 256*8*32000 = 65,536,000 elems (262 MB)
//
// Strategy (round 1 — correctness + basic MFMA):
//  - fp32 path: merge GEMM, x_proj GEMM (biases b_ih+b_hh folded), elementwise
//    gates/c/h (keeps recurrence error small)
//  - bf16 MFMA path: h@W_hh^T per step, and one batched logits GEMM
//    [2048 x 32000 x 512] with fused bias + (t,n)->[n][t][v] output remap.

#define GLOBAL_AS __attribute__((address_space(1)))
#define LDS_AS __attribute__((address_space(3)))

typedef __attribute__((ext_vector_type(8))) short short8;   // 8 x bf16 (4 VGPRs)
typedef __attribute__((ext_vector_type(4))) float f32x4;    // MFMA accumulator

constexpr int N_  = 256;
constexpr int CIN = 1024;
constexpr int H_  = 512;
constexpr int G4  = 2048;   // 4*H
constexpr int V_  = 32000;
constexpr int T_  = 8;

__device__ inline short f2bf(float f) {   // fp32 -> bf16, round-to-nearest-even
  union { float f; unsigned u; } v; v.f = f;
  unsigned r = v.u + 0x7fffu + ((v.u >> 16) & 1u);
  return (short)(r >> 16);
}

__device__ inline void async16(const void* g, void* l) {
  // global -> LDS direct copy, 16 B per lane; LDS dest = wave-uniform base + lane*16
  __builtin_amdgcn_global_load_lds((const GLOBAL_AS unsigned*)g,
                                   (LDS_AS unsigned*)l, 16, 0, 0);
}

__device__ inline float sigm(float x) { return 1.0f / (1.0f + __expf(-x)); }
__device__ inline float tanh_fast(float x) {
  x = fminf(15.0f, fmaxf(-15.0f, x));
  float e = __expf(2.0f * x);
  return (e - 1.0f) / (e + 1.0f);
}

// ---------------- fp32 -> bf16 weight conversion (4 elems/thread) -------------
__global__ __launch_bounds__(256) void cvt_bf16_4(const float* __restrict__ in,
                                                  short* __restrict__ out, int n4) {
  int i = blockIdx.x * 256 + threadIdx.x;
  if (i >= n4) return;
  float4 v = ((const float4*)in)[i];
  short4 s;
  s.x = f2bf(v.x); s.y = f2bf(v.y); s.z = f2bf(v.z); s.w = f2bf(v.w);
  ((short4*)out)[i] = s;
}

// ---------------- fp32 tiled GEMM: C[M,N] = A[M,K] @ B[N,K]^T + b1 + b2 -------
// 64x64 tile, BK=16, 256 threads, each thread 4x4 outputs. LDS stored
// transposed [k][m] with +4 pad (2-way bank aliasing only, which is free).
template<int BM, int BN, int BK>
__global__ __launch_bounds__(256) void gemm_f32_bt(
    const float* __restrict__ A, const float* __restrict__ B,
    const float* __restrict__ b1, const float* __restrict__ b2,
    float* __restrict__ C, int M, int N, int K)
{
  __shared__ float As[BK][BM + 4];
  __shared__ float Bs[BK][BN + 4];
  const int tid = threadIdx.x;
  const int m0 = blockIdx.y * BM, n0 = blockIdx.x * BN;
  const int tm = (tid >> 4) << 2;     // 0..60
  const int tn = (tid & 15) << 2;     // 0..60
  const int row = tid >> 2, q = (tid & 3) << 2;
  float acc[4][4] = {};

  for (int kc = 0; kc < K; kc += BK) {
    float4 av = *(const float4*)&A[(size_t)(m0 + row) * K + kc + q];
    float4 bv = *(const float4*)&B[(size_t)(n0 + row) * K + kc + q];
    As[q + 0][row] = av.x; As[q + 1][row] = av.y;
    As[q + 2][row] = av.z; As[q + 3][row] = av.w;
    Bs[q + 0][row] = bv.x; Bs[q + 1][row] = bv.y;
    Bs[q + 2][row] = bv.z; Bs[q + 3][row] = bv.w;
    __syncthreads();
#pragma unroll
    for (int kk = 0; kk < BK; ++kk) {
      float4 a4 = *(const float4*)&As[kk][tm];
      float4 b4 = *(const float4*)&Bs[kk][tn];
      float aa[4] = {a4.x, a4.y, a4.z, a4.w};
      float bb[4] = {b4.x, b4.y, b4.z, b4.w};
#pragma unroll
      for (int i = 0; i < 4; ++i)
#pragma unroll
        for (int j = 0; j < 4; ++j) acc[i][j] += aa[i] * bb[j];
    }
    __syncthreads();
  }
#pragma unroll
  for (int i = 0; i < 4; ++i)
#pragma unroll
    for (int j = 0; j < 4; ++j) {
      int ng = n0 + tn + j;
      float v = acc[i][j];
      if (b1) v += b1[ng];
      if (b2) v += b2[ng];
      C[(size_t)(m0 + tm + i) * N + ng] = v;
    }
}

// ------------- bf16 MFMA GEMM-BT: C[M,N] = A[M,K]bf16 @ B[N,K]bf16^T ---------
// A, B both K-contiguous. 256 threads = 4 waves in 2x2; each wave computes
// (BM/2)x(BN/2) via RTxCT 16x16x32 MFMAs. global_load_lds width-16 staging.
// REMAP=true: C index = [n=mg&255][t=mg>>8][v] for out[N,T,V]; bias added.
template<int BM, int BN, bool REMAP>
__global__ __launch_bounds__(256) void gemm_bf16_bt(
    const short* __restrict__ A, const short* __restrict__ B,
    const float* __restrict__ bias, float* __restrict__ C,
    int M, int N, int K)
{
  constexpr int RT = BM / 32;    // 16-row tiles per wave
  constexpr int CT = BN / 32;    // 16-col tiles per wave
  __shared__ short As[BM * 32];
  __shared__ short Bs[BN * 32];

  const int tid = threadIdx.x;
  const int lane = tid & 63;
  const int w = tid >> 6;
  const int wr = w >> 1, wc = w & 1;
  const int m0 = blockIdx.y * BM;
  const int n0 = blockIdx.x * BN;
  const int rlane = lane & 15;
  const int klane = (lane >> 4) * 8;

  f32x4 acc[RT][CT] = {};

  for (int kc = 0; kc < K; kc += 32) {
    // stage A tile (BM x 32 bf16): chunk idx -> row=idx>>2, 8-elem group q=idx&3
#pragma unroll
    for (int it = 0; it < (BM * 4) / 256; ++it) {
      int idx = it * 256 + tid;
      const short* g = A + (size_t)(m0 + (idx >> 2)) * K + kc + (idx & 3) * 8;
      async16(g, &As[(size_t)(it * 256 + (tid & ~63)) * 8]);
    }
#pragma unroll
    for (int it = 0; it < (BN * 4) / 256; ++it) {
      int idx = it * 256 + tid;
      const short* g = B + (size_t)(n0 + (idx >> 2)) * K + kc + (idx & 3) * 8;
      async16(g, &Bs[(size_t)(it * 256 + (tid & ~63)) * 8]);
    }
    __syncthreads();   // compiler emits s_waitcnt vmcnt(0) before s_barrier

    short8 af[RT], bf[CT];
#pragma unroll
    for (int rt = 0; rt < RT; ++rt) {
      int m_l = wr * (RT * 16) + rt * 16 + rlane;
      af[rt] = *(const short8*)&As[m_l * 32 + klane];
    }
#pragma unroll
    for (int ct = 0; ct < CT; ++ct) {
      int n_l = wc * (CT * 16) + ct * 16 + rlane;
      bf[ct] = *(const short8*)&Bs[n_l * 32 + klane];
    }
#pragma unroll
    for (int rt = 0; rt < RT; ++rt)
#pragma unroll
      for (int ct = 0; ct < CT; ++ct)
        acc[rt][ct] = __builtin_amdgcn_mfma_f32_16x16x32_bf16(af[rt], bf[ct],
                                                              acc[rt][ct], 0, 0, 0);
    __syncthreads();
  }

  // C/D layout (m89-verified): col = lane&15, row = (lane>>4)*4 + reg
#pragma unroll
  for (int rt = 0; rt < RT; ++rt)
#pragma unroll
    for (int ct = 0; ct < CT; ++ct)
#pragma unroll
      for (int r = 0; r < 4; ++r) {
        int mg = m0 + wr * (RT * 16) + rt * 16 + (lane >> 4) * 4 + r;
        int ng = n0 + wc * (CT * 16) + ct * 16 + rlane;
        float v = acc[rt][ct][r];
        if (bias) v += bias[ng];
        if (REMAP) {
          // Hall row m = t*256 + n  ->  out[n][t][v]
          int t = mg >> 8, nb = mg & 255;
          C[(size_t)nb * (T_ * V_) + (size_t)t * V_ + ng] = v;
        } else {
          C[(size_t)mg * N + ng] = v;
        }
      }
}

// ---------------- LSTM elementwise: gates -> c, h(bf16 into Hall[t]) ----------
// X already contains x_proj + b_ih + b_hh. gates (fp32) = h@W_hh^T (no bias),
// null for step 0 (h=0, c=0).
__global__ __launch_bounds__(256) void lstm_ew(
    const float* __restrict__ X, const float* __restrict__ gates,
    float* __restrict__ c, short* __restrict__ hall_t, int first)
{
  int idx = blockIdx.x * 256 + threadIdx.x;        // 0 .. 256*512-1
  int n = idx >> 9, j = idx & 511;
  const float* xr = X + (size_t)n * G4;
  float pi = xr[j], pf = xr[H_ + j], pg = xr[2 * H_ + j], po = xr[3 * H_ + j];
  if (!first) {
    const float* gr = gates + (size_t)n * G4;
    pi += gr[j]; pf += gr[H_ + j]; pg += gr[2 * H_ + j]; po += gr[3 * H_ + j];
  }
  float ii = sigm(pi), ff = sigm(pf), gg = tanh_fast(pg), oo = sigm(po);
  float cc = first ? (ii * gg) : (ff * c[idx] + ii * gg);
  c[idx] = cc;
  hall_t[idx] = f2bf(oo * tanh_fast(cc));
}

extern "C" void kernel_launch(void* const* d_in, const int* in_sizes, int n_in,
                              void* d_out, int out_size, void* d_ws, size_t ws_size,
                              hipStream_t stream)
{
  (void)in_sizes; (void)n_in; (void)out_size; (void)ws_size;
  const float* context = (const float*)d_in[0];
  const float* W_merge = (const float*)d_in[1];
  const float* b_merge = (const float*)d_in[2];
  const float* W_ih    = (const float*)d_in[3];
  const float* W_hh    = (const float*)d_in[4];
  const float* b_ih    = (const float*)d_in[5];
  const float* b_hh    = (const float*)d_in[6];
  const float* W_out   = (const float*)d_in[7];
  const float* b_out   = (const float*)d_in[8];
  float* out = (float*)d_out;

  // workspace layout (~40.3 MB total)
  char* p = (char*)d_ws;
  short* Wout_b = (short*)p;  p += (size_t)V_ * H_ * 2;     // 32.77 MB
  short* Whh_b  = (short*)p;  p += (size_t)G4 * H_ * 2;     // 2 MB
  short* Hall   = (short*)p;  p += (size_t)T_ * N_ * H_ * 2;// 2 MB  [t][n][k] bf16
  float* ctx    = (float*)p;  p += (size_t)N_ * H_ * 4;     // 0.5 MB
  float* X      = (float*)p;  p += (size_t)N_ * G4 * 4;     // 2 MB
  float* c      = (float*)p;  p += (size_t)N_ * H_ * 4;     // 0.5 MB
  float* gates  = (float*)p;  p += (size_t)N_ * G4 * 4;     // 2 MB

  // weight conversions (counts divisible by 4)
  cvt_bf16_4<<<(V_ * H_ / 4 + 255) / 256, 256, 0, stream>>>(W_out, Wout_b, V_ * H_ / 4);
  cvt_bf16_4<<<(G4 * H_ / 4 + 255) / 256, 256, 0, stream>>>(W_hh, Whh_b, G4 * H_ / 4);

  // ctx = context @ W_merge^T + b_merge          [256 x 512], K=1024
  gemm_f32_bt<64, 64, 16><<<dim3(H_ / 64, N_ / 64), 256, 0, stream>>>(
      context, W_merge, b_merge, nullptr, ctx, N_, H_, CIN);
  // X = ctx @ W_ih^T + b_ih + b_hh               [256 x 2048], K=512
  gemm_f32_bt<64, 64, 16><<<dim3(G4 / 64, N_ / 64), 256, 0, stream>>>(
      ctx, W_ih, b_ih, b_hh, X, N_, G4, H_);

  // step 0: h=0, c=0 -> gates = X
  lstm_ew<<<N_ * H_ / 256, 256, 0, stream>>>(X, nullptr, c, Hall, 1);
  // steps 1..7
  for (int t = 1; t < T_; ++t) {
    gemm_bf16_bt<64, 64, false><<<dim3(G4 / 64, N_ / 64), 256, 0, stream>>>(
        Hall + (size_t)(t - 1) * N_ * H_, Whh_b, nullptr, gates, N_, G4, H_);
    lstm_ew<<<N_ * H_ / 256, 256, 0, stream>>>(X, gates, c,
                                               Hall + (size_t)t * N_ * H_, 0);
  }

  // logits: [2048 x 32000] = Hall @ W_out^T + b_out, remapped to out[N,T,V]
  gemm_bf16_bt<128, 128, true><<<dim3(V_ / 128, (T_ * N_) / 128), 256, 0, stream>>>(
      Hall, Wout_b, b_out, out, T_ * N_, V_, H_);
}

// Round 2
// 533.549 us; speedup vs baseline: 1.1964x; 1.1964x over previous
//
#include <hip/hip_runtime.h>

// VarDecoder: N=256, CAT_IN=1024, H=512, V=32000, T=8
// out[n][t][v] fp32, 65,536,000 elems (262 MB)
//
// Round 2: all GEMMs bf16-MFMA; per-step [gates GEMM + elementwise] fused into
// one kernel (block owns (n,j) tile, computes all 4 gate tiles, LDS exchange).
// Launches: cvt_Wout, cvt_multi, merge, x_proj, 8x lstm_step, logits = 13.

#define GLOBAL_AS __attribute__((address_space(1)))
#define LDS_AS __attribute__((address_space(3)))

typedef __attribute__((ext_vector_type(8))) short short8;   // 8 x bf16 (4 VGPRs)
typedef __attribute__((ext_vector_type(4))) float f32x4;    // MFMA accumulator

constexpr int N_  = 256;
constexpr int CIN = 1024;
constexpr int H_  = 512;
constexpr int G4  = 2048;   // 4*H
constexpr int V_  = 32000;
constexpr int T_  = 8;

__device__ inline short f2bf(float f) {   // fp32 -> bf16 RNE
  union { float f; unsigned u; } v; v.f = f;
  unsigned r = v.u + 0x7fffu + ((v.u >> 16) & 1u);
  return (short)(r >> 16);
}

__device__ inline void async16(const void* g, void* l) {
  __builtin_amdgcn_global_load_lds((const GLOBAL_AS unsigned*)g,
                                   (LDS_AS unsigned*)l, 16, 0, 0);
}

__device__ inline float sigm(float x) { return 1.0f / (1.0f + __expf(-x)); }
__device__ inline float tanh_fast(float x) {
  x = fminf(15.0f, fmaxf(-15.0f, x));
  float e = __expf(2.0f * x);
  return (e - 1.0f) / (e + 1.0f);
}

// ---------------- fp32 -> bf16 conversion, 4 elems/thread ---------------------
__global__ __launch_bounds__(256) void cvt_bf16_4(const float* __restrict__ in,
                                                  short* __restrict__ out, int n4) {
  int i = blockIdx.x * 256 + threadIdx.x;
  if (i >= n4) return;
  float4 v = ((const float4*)in)[i];
  short4 s;
  s.x = f2bf(v.x); s.y = f2bf(v.y); s.z = f2bf(v.z); s.w = f2bf(v.w);
  ((short4*)out)[i] = s;
}

// one launch converting 4 small arrays (context, W_merge, W_ih, W_hh)
__global__ __launch_bounds__(256) void cvt_multi(
    const float* __restrict__ s0, short* __restrict__ d0, int c0,
    const float* __restrict__ s1, short* __restrict__ d1, int c1,
    const float* __restrict__ s2, short* __restrict__ d2, int c2,
    const float* __restrict__ s3, short* __restrict__ d3, int c3) {
  int i = blockIdx.x * 256 + threadIdx.x;
  const float* s; short* d; int k;
  if (i < c0)                { s = s0; d = d0; k = i; }
  else if (i < c0 + c1)      { s = s1; d = d1; k = i - c0; }
  else if (i < c0 + c1 + c2) { s = s2; d = d2; k = i - c0 - c1; }
  else if (i < c0 + c1 + c2 + c3) { s = s3; d = d3; k = i - c0 - c1 - c2; }
  else return;
  float4 v = ((const float4*)s)[k];
  short4 o;
  o.x = f2bf(v.x); o.y = f2bf(v.y); o.z = f2bf(v.z); o.w = f2bf(v.w);
  ((short4*)d)[k] = o;
}

// ------------- bf16 MFMA GEMM-BT: C[M,N] = A[M,K] @ B[N,K]^T -----------------
// MODE 0: C fp32 + bias1 + bias2;  MODE 1: C bf16 + bias1;
// MODE 2: C fp32, row m = t*256+n remapped to out[n][t][v], + bias1.
template<int BM, int BN, int MODE>
__global__ __launch_bounds__(256) void gemm_bf16_bt(
    const short* __restrict__ A, const short* __restrict__ B,
    const float* __restrict__ bias1, const float* __restrict__ bias2,
    void* __restrict__ Cv, int M, int N, int K)
{
  constexpr int RT = BM / 32;
  constexpr int CT = BN / 32;
  __shared__ short As[BM * 32];
  __shared__ short Bs[BN * 32];

  const int tid = threadIdx.x;
  const int lane = tid & 63;
  const int w = tid >> 6;
  const int wr = w >> 1, wc = w & 1;
  const int m0 = blockIdx.y * BM;
  const int n0 = blockIdx.x * BN;
  const int rlane = lane & 15;
  const int klane = (lane >> 4) * 8;

  f32x4 acc[RT][CT] = {};

  for (int kc = 0; kc < K; kc += 32) {
#pragma unroll
    for (int it = 0; it < (BM * 4) / 256; ++it) {
      int idx = it * 256 + tid;
      const short* g = A + (size_t)(m0 + (idx >> 2)) * K + kc + (idx & 3) * 8;
      async16(g, &As[(size_t)(it * 256 + (tid & ~63)) * 8]);
    }
#pragma unroll
    for (int it = 0; it < (BN * 4) / 256; ++it) {
      int idx = it * 256 + tid;
      const short* g = B + (size_t)(n0 + (idx >> 2)) * K + kc + (idx & 3) * 8;
      async16(g, &Bs[(size_t)(it * 256 + (tid & ~63)) * 8]);
    }
    __syncthreads();

    short8 af[RT], bf[CT];
#pragma unroll
    for (int rt = 0; rt < RT; ++rt)
      af[rt] = *(const short8*)&As[(wr * (RT * 16) + rt * 16 + rlane) * 32 + klane];
#pragma unroll
    for (int ct = 0; ct < CT; ++ct)
      bf[ct] = *(const short8*)&Bs[(wc * (CT * 16) + ct * 16 + rlane) * 32 + klane];
#pragma unroll
    for (int rt = 0; rt < RT; ++rt)
#pragma unroll
      for (int ct = 0; ct < CT; ++ct)
        acc[rt][ct] = __builtin_amdgcn_mfma_f32_16x16x32_bf16(af[rt], bf[ct],
                                                              acc[rt][ct], 0, 0, 0);
    __syncthreads();
  }

  // C/D layout: col = lane&15, row = (lane>>4)*4 + reg
#pragma unroll
  for (int ct = 0; ct < CT; ++ct) {
    int ng = n0 + wc * (CT * 16) + ct * 16 + rlane;
    float bv = (bias1 ? bias1[ng] : 0.0f) + (bias2 ? bias2[ng] : 0.0f);
#pragma unroll
    for (int rt = 0; rt < RT; ++rt)
#pragma unroll
      for (int r = 0; r < 4; ++r) {
        int mg = m0 + wr * (RT * 16) + rt * 16 + (lane >> 4) * 4 + r;
        float v = acc[rt][ct][r] + bv;
        if (MODE == 2) {
          int t = mg >> 8, nb = mg & 255;
          ((float*)Cv)[(size_t)nb * (T_ * V_) + (size_t)t * V_ + ng] = v;
        } else if (MODE == 1) {
          ((short*)Cv)[(size_t)mg * N + ng] = f2bf(v);
        } else {
          ((float*)Cv)[(size_t)mg * N + ng] = v;
        }
      }
  }
}

// ---------------- fused LSTM step: gates GEMM + elementwise -------------------
// Block owns n-tile 32 x j-tile 32. Wave w computes gate w's 32x32 preact tile
// (acc init from X which already holds x_proj + b_ih + b_hh), K=512 over
// Hprev(bf16) @ W_hh^T(bf16). Gate tiles exchanged via LDS; elementwise
// updates c (fp32, global) and writes h (bf16) into Hall[t].
__global__ __launch_bounds__(256) void lstm_step(
    const short* __restrict__ Hprev,   // [256][512] bf16 (ignored if first)
    const short* __restrict__ Whh,     // [2048][512] bf16
    const float* __restrict__ X,       // [256][2048] fp32
    float* __restrict__ c,             // [256][512] fp32 (uninit if first)
    short* __restrict__ Hnext,         // [256][512] bf16
    int first)
{
  __shared__ char lds_raw[16384];
  short* As = (short*)lds_raw;            // [32][32] bf16, 2 KB
  short* Bs = (short*)(lds_raw + 4096);   // [128][32] bf16, 8 KB (at 4K..12K)
  float* G  = (float*)lds_raw;            // [4][32][32] fp32, 16 KB overlay

  const int tid = threadIdx.x;
  const int lane = tid & 63;
  const int w = tid >> 6;            // gate index 0..3 (i,f,g,o)
  const int j0 = blockIdx.x * 32;    // 16 j-tiles
  const int n0 = blockIdx.y * 32;    // 8 n-tiles
  const int rlane = lane & 15;
  const int klane = (lane >> 4) * 8;
  const int qrow = (lane >> 4) * 4;  // C-layout row base

  // acc init from X: row m = rt*16 + qrow + r (n), col = ct*16 + rlane (j)
  f32x4 acc[2][2];
#pragma unroll
  for (int rt = 0; rt < 2; ++rt)
#pragma unroll
    for (int ct = 0; ct < 2; ++ct)
#pragma unroll
      for (int r = 0; r < 4; ++r)
        acc[rt][ct][r] = X[(size_t)(n0 + rt * 16 + qrow + r) * G4
                           + w * H_ + j0 + ct * 16 + rlane];

  if (!first) {
    for (int kc = 0; kc < H_; kc += 32) {
      // As: 32 rows x 32 k = 128 chunks of 8 bf16; waves 0,1 only
      if (w < 2)
        async16(Hprev + (size_t)(n0 + (tid >> 2)) * H_ + kc + (tid & 3) * 8,
                &As[(size_t)(tid & ~63) * 8]);
      // Bs: 128 rows (4 gates x 32 j) x 32 k = 512 chunks; 2 passes
#pragma unroll
      for (int p = 0; p < 2; ++p) {
        int idx = p * 256 + tid;
        int br = idx >> 2, q = idx & 3;
        int g = br >> 5, jj = br & 31;
        async16(Whh + (size_t)(g * H_ + j0 + jj) * H_ + kc + q * 8,
                &Bs[(size_t)(idx & ~63) * 8]);
      }
      __syncthreads();
      short8 a0 = *(const short8*)&As[(0 * 16 + rlane) * 32 + klane];
      short8 a1 = *(const short8*)&As[(1 * 16 + rlane) * 32 + klane];
      short8 b0 = *(const short8*)&Bs[(w * 32 + 0 * 16 + rlane) * 32 + klane];
      short8 b1 = *(const short8*)&Bs[(w * 32 + 1 * 16 + rlane) * 32 + klane];
      acc[0][0] = __builtin_amdgcn_mfma_f32_16x16x32_bf16(a0, b0, acc[0][0], 0, 0, 0);
      acc[0][1] = __builtin_amdgcn_mfma_f32_16x16x32_bf16(a0, b1, acc[0][1], 0, 0, 0);
      acc[1][0] = __builtin_amdgcn_mfma_f32_16x16x32_bf16(a1, b0, acc[1][0], 0, 0, 0);
      acc[1][1] = __builtin_amdgcn_mfma_f32_16x16x32_bf16(a1, b1, acc[1][1], 0, 0, 0);
      __syncthreads();
    }
  }

  // exchange gate tiles via LDS: G[gate][n][j]
#pragma unroll
  for (int rt = 0; rt < 2; ++rt)
#pragma unroll
    for (int ct = 0; ct < 2; ++ct)
#pragma unroll
      for (int r = 0; r < 4; ++r)
        G[(size_t)(w * 32 + rt * 16 + qrow + r) * 32 + ct * 16 + rlane] =
            acc[rt][ct][r];
  __syncthreads();

  // elementwise: thread -> (n = tid>>3, j = (tid&7)*4 .. +3)
  int n = tid >> 3, jq = tid & 7;
  float4 gi = ((const float4*)G)[(0 * 32 + n) * 8 + jq];
  float4 gf = ((const float4*)G)[(1 * 32 + n) * 8 + jq];
  float4 gg = ((const float4*)G)[(2 * 32 + n) * 8 + jq];
  float4 go = ((const float4*)G)[(3 * 32 + n) * 8 + jq];
  size_t cix = (size_t)(n0 + n) * H_ + j0 + jq * 4;
  float4 cold = make_float4(0.f, 0.f, 0.f, 0.f);
  if (!first) cold = *(const float4*)&c[cix];
  float ci[4] = {gi.x, gi.y, gi.z, gi.w};
  float cf[4] = {gf.x, gf.y, gf.z, gf.w};
  float cg[4] = {gg.x, gg.y, gg.z, gg.w};
  float co[4] = {go.x, go.y, go.z, go.w};
  float cc[4] = {cold.x, cold.y, cold.z, cold.w};
  float4 cnew; short4 hnew;
  float* cn = &cnew.x;
  short hv[4];
#pragma unroll
  for (int e = 0; e < 4; ++e) {
    float ii = sigm(ci[e]), ff = sigm(cf[e]), g2 = tanh_fast(cg[e]), oo = sigm(co[e]);
    float cval = ff * cc[e] + ii * g2;
    cn[e] = cval;
    hv[e] = f2bf(oo * tanh_fast(cval));
  }
  hnew.x = hv[0]; hnew.y = hv[1]; hnew.z = hv[2]; hnew.w = hv[3];
  *(float4*)&c[cix] = cnew;
  *(short4*)&Hnext[cix] = hnew;
}

extern "C" void kernel_launch(void* const* d_in, const int* in_sizes, int n_in,
                              void* d_out, int out_size, void* d_ws, size_t ws_size,
                              hipStream_t stream)
{
  (void)in_sizes; (void)n_in; (void)out_size; (void)ws_size;
  const float* context = (const float*)d_in[0];
  const float* W_merge = (const float*)d_in[1];
  const float* b_merge = (const float*)d_in[2];
  const float* W_ih    = (const float*)d_in[3];
  const float* W_hh    = (const float*)d_in[4];
  const float* b_ih    = (const float*)d_in[5];
  const float* b_hh    = (const float*)d_in[6];
  const float* W_out   = (const float*)d_in[7];
  const float* b_out   = (const float*)d_in[8];
  float* out = (float*)d_out;

  // workspace layout (~43 MB)
  char* p = (char*)d_ws;
  short* Wout_b = (short*)p;  p += (size_t)V_ * H_ * 2;        // 32.77 MB
  short* Whh_b  = (short*)p;  p += (size_t)G4 * H_ * 2;        // 2 MB
  short* Wih_b  = (short*)p;  p += (size_t)G4 * H_ * 2;        // 2 MB
  short* Wmrg_b = (short*)p;  p += (size_t)H_ * CIN * 2;       // 1 MB
  short* Ctxin_b= (short*)p;  p += (size_t)N_ * CIN * 2;       // 0.5 MB
  short* Ctx_b  = (short*)p;  p += (size_t)N_ * H_ * 2;        // 0.25 MB
  short* Hall   = (short*)p;  p += (size_t)T_ * N_ * H_ * 2;   // 2 MB [t][n][k]
  float* X      = (float*)p;  p += (size_t)N_ * G4 * 4;        // 2 MB
  float* c      = (float*)p;  p += (size_t)N_ * H_ * 4;        // 0.5 MB

  // conversions
  cvt_bf16_4<<<(V_ * H_ / 4 + 255) / 256, 256, 0, stream>>>(W_out, Wout_b, V_ * H_ / 4);
  {
    int c0 = N_ * CIN / 4, c1 = H_ * CIN / 4, c2 = G4 * H_ / 4, c3 = G4 * H_ / 4;
    int tot = c0 + c1 + c2 + c3;
    cvt_multi<<<(tot + 255) / 256, 256, 0, stream>>>(
        context, Ctxin_b, c0, W_merge, Wmrg_b, c1,
        W_ih, Wih_b, c2, W_hh, Whh_b, c3);
  }

  // ctx(bf16) = context @ W_merge^T + b_merge    [256 x 512], K=1024
  gemm_bf16_bt<64, 64, 1><<<dim3(H_ / 64, N_ / 64), 256, 0, stream>>>(
      Ctxin_b, Wmrg_b, b_merge, nullptr, Ctx_b, N_, H_, CIN);
  // X = ctx @ W_ih^T + b_ih + b_hh               [256 x 2048], K=512
  gemm_bf16_bt<64, 64, 0><<<dim3(G4 / 64, N_ / 64), 256, 0, stream>>>(
      Ctx_b, Wih_b, b_ih, b_hh, X, N_, G4, H_);

  // 8 fused LSTM steps
  for (int t = 0; t < T_; ++t) {
    const short* hp = (t == 0) ? Hall : Hall + (size_t)(t - 1) * N_ * H_;
    lstm_step<<<dim3(H_ / 32, N_ / 32), 256, 0, stream>>>(
        hp, Whh_b, X, c, Hall + (size_t)t * N_ * H_, t == 0 ? 1 : 0);
  }

  // logits: [2048 x 32000] = Hall @ W_out^T + b_out -> out[N,T,V]
  gemm_bf16_bt<128, 128, 2><<<dim3(V_ / 128, (T_ * N_) / 128), 256, 0, stream>>>(
      Hall, Wout_b, b_out, nullptr, out, T_ * N_, V_, H_);
}